// Round 5
// baseline (497.458 us; speedup 1.0000x reference)
//
#include <hip/hip_runtime.h>
#include <hip/hip_bf16.h>

#define DEV __device__ __forceinline__

typedef unsigned short u16;
typedef __attribute__((ext_vector_type(4))) float f32x4;
typedef __attribute__((ext_vector_type(8))) short s16x8;

// problem constants
static constexpr int Bc = 2, Hc = 16, Sc = 4096, Dc = 1024, HDc = 64;

DEV u16 f2bf(float f) {
  unsigned x = __float_as_uint(f);
  x += 0x7FFFu + ((x >> 16) & 1u);   // RNE
  return (u16)(x >> 16);
}
DEV float bf2f(u16 u) { return __uint_as_float(((unsigned)u) << 16); }

DEV unsigned cvtpk_bf16(float lo, float hi) {   // word = bf16(lo) | bf16(hi)<<16
  unsigned r;
  asm("v_cvt_pk_bf16_f32 %0, %1, %2" : "=v"(r) : "v"(lo), "v"(hi));
  return r;
}

DEV void gload_lds16(const void* g, void* l) {
  __builtin_amdgcn_global_load_lds((const __attribute__((address_space(1))) void*)g,
                                   (__attribute__((address_space(3))) void*)l, 16, 0, 0);
}

DEV f32x4 mfma16(s16x8 a, s16x8 b, f32x4 c) {
  return __builtin_amdgcn_mfma_f32_16x16x32_bf16(a, b, c, 0, 0, 0);
}

DEV f32x4 fzero4() { f32x4 v; v[0] = v[1] = v[2] = v[3] = 0.f; return v; }

// ---------------- elementwise f32 -> bf16 ----------------
__global__ void cvt_f32_bf16(const float* __restrict__ in, u16* __restrict__ out, size_t n) {
  size_t i = ((size_t)blockIdx.x * blockDim.x + threadIdx.x) * 4;
  size_t stride = (size_t)gridDim.x * blockDim.x * 4;
  for (; i < n; i += stride) {
    float4 v = *(const float4*)(in + i);
    u16 a = f2bf(v.x), b = f2bf(v.y), c = f2bf(v.z), d = f2bf(v.w);
    *(ushort4*)(out + i) = make_ushort4(a, b, c, d);
  }
}

// ---------------- transpose + convert: out[c][r] = bf16(in[r][c]) ----------------
__global__ void transpose_cvt(const float* __restrict__ in, u16* __restrict__ out, int R, int C) {
  __shared__ u16 t[64][72];
  int nct = C >> 6;
  int tr = blockIdx.x / nct, tc = blockIdx.x % nct;
  int r0 = tr << 6, c0 = tc << 6;
  int lr = threadIdx.x >> 2;
  int lc0 = (threadIdx.x & 3) << 4;
  const float* src = in + (size_t)(r0 + lr) * C + c0 + lc0;
#pragma unroll
  for (int j = 0; j < 16; j += 4) {
    float4 v = *(const float4*)(src + j);
    t[lr][lc0 + j + 0] = f2bf(v.x);
    t[lr][lc0 + j + 1] = f2bf(v.y);
    t[lr][lc0 + j + 2] = f2bf(v.z);
    t[lr][lc0 + j + 3] = f2bf(v.w);
  }
  __syncthreads();
  u16* dst = out + (size_t)(c0 + lr) * R + r0 + lc0;
#pragma unroll
  for (int j = 0; j < 16; j += 4) {
    u16 a = t[lc0 + j + 0][lr], b = t[lc0 + j + 1][lr], c = t[lc0 + j + 2][lr], d = t[lc0 + j + 3][lr];
    *(ushort4*)(dst + j) = make_ushort4(a, b, c, d);
  }
}

// ---------------- GEMM: C[m][n] = A[m][:] . BT[n][:] + bias[n] ----------------
template <int MODE>
__global__ __launch_bounds__(256, 2) void gemm128(
    const u16* __restrict__ A, const u16* __restrict__ BT, const float* __restrict__ bias,
    void* __restrict__ out0, u16* __restrict__ out1, u16* __restrict__ out2,
    int N, int K, int grid_n) {
  __shared__ u16 Al[128 * 64];
  __shared__ u16 Bl[128 * 64];
  int bid = blockIdx.x;
  int bn = bid % grid_n, bm = bid / grid_n;
  int m0 = bm * 128, n0 = bn * 128;
  int tid = threadIdx.x, lane = tid & 63, wid = tid >> 6;
  int wm = wid >> 1, wn = wid & 1;
  int fr = lane & 15, fg = lane >> 4;

  f32x4 acc[4][4];
#pragma unroll
  for (int mi = 0; mi < 4; ++mi)
#pragma unroll
    for (int ni = 0; ni < 4; ++ni) acc[mi][ni] = fzero4();

  for (int kt = 0; kt < K; kt += 64) {
    const u16* Ag = A + (size_t)m0 * K + kt;
    const u16* Bg = BT + (size_t)n0 * K + kt;
#pragma unroll
    for (int it = 0; it < 4; ++it) {
      int L = it * 4096 + wid * 1024 + lane * 16;  // byte offset in 16KB tile
      int row = L >> 7;
      int sch = ((L >> 4) & 7) ^ (row & 7);
      gload_lds16(Ag + (size_t)row * K + sch * 8, (char*)Al + it * 4096 + wid * 1024);
      gload_lds16(Bg + (size_t)row * K + sch * 8, (char*)Bl + it * 4096 + wid * 1024);
    }
    __syncthreads();
#pragma unroll
    for (int c = 0; c < 2; ++c) {
      s16x8 af[4], bfr[4];
#pragma unroll
      for (int mi = 0; mi < 4; ++mi) {
        int row = wm * 64 + mi * 16 + fr;
        int ch = (c * 4 + fg) ^ (row & 7);
        af[mi] = *(const s16x8*)((const char*)Al + row * 128 + ch * 16);
      }
#pragma unroll
      for (int ni = 0; ni < 4; ++ni) {
        int row = wn * 64 + ni * 16 + fr;
        int ch = (c * 4 + fg) ^ (row & 7);
        bfr[ni] = *(const s16x8*)((const char*)Bl + row * 128 + ch * 16);
      }
#pragma unroll
      for (int mi = 0; mi < 4; ++mi)
#pragma unroll
        for (int ni = 0; ni < 4; ++ni) acc[mi][ni] = mfma16(af[mi], bfr[ni], acc[mi][ni]);
    }
    __syncthreads();
  }

  if constexpr (MODE == 0) {
    u16* qb = (u16*)out0;
    u16* kb = out1;
    u16* vT = out2;
#pragma unroll
    for (int ni = 0; ni < 4; ++ni) {
      int n = n0 + wn * 64 + ni * 16 + fr;
      float bv = bias[n];
      int h = n / 192;
      int c = n % 192;
      int part = c >> 6;
      int e = c & 63;
#pragma unroll
      for (int mi = 0; mi < 4; ++mi) {
        int m = m0 + wm * 64 + mi * 16 + fg * 4;
        int b = m >> 12;
        int s = m & 4095;
        size_t bh = (size_t)b * Hc + h;
        if (part == 2) {
          u16 a0 = f2bf(acc[mi][ni][0] + bv), a1 = f2bf(acc[mi][ni][1] + bv);
          u16 a2 = f2bf(acc[mi][ni][2] + bv), a3 = f2bf(acc[mi][ni][3] + bv);
          *(ushort4*)(vT + ((bh * HDc + e) * (size_t)Sc + s)) = make_ushort4(a0, a1, a2, a3);
        } else {
          u16* dst = (part == 0 ? qb : kb) + ((bh * Sc + s) * (size_t)HDc + e);
#pragma unroll
          for (int r = 0; r < 4; ++r) dst[(size_t)r * HDc] = f2bf(acc[mi][ni][r] + bv);
        }
      }
    }
  } else {
    float* O = (float*)out0;
#pragma unroll
    for (int ni = 0; ni < 4; ++ni) {
      int n = n0 + wn * 64 + ni * 16 + fr;
      float bv = bias[n];
#pragma unroll
      for (int mi = 0; mi < 4; ++mi) {
        int m = m0 + wm * 64 + mi * 16 + fg * 4;
#pragma unroll
        for (int r = 0; r < 4; ++r) O[(size_t)(m + r) * N + n] = acc[mi][ni][r] + bv;
      }
    }
  }
}

// ---------------- flash attention, 8-wave blocks ----------------
// grid 1024 = qt(32) x b(2) x h(16); block 512 = 8 waves; q-tile = 128 rows,
// wave w owns rows w*16..w*16+15 (lane fr). All 8 waves share one K/V tile in
// LDS (single-buffered, gload_lds staged) -> staging bytes amortized over 2x
// compute vs R2. Swapped QK^T: q lane-local; softmax per-lane + 2 shfl.
// MB=1: mask bf16 (natural domain); MB=0: f32 fallback.
template <int MB>
__global__ __launch_bounds__(512, 6) void attn_kernel(
    const u16* __restrict__ qb, const u16* __restrict__ kb, const u16* __restrict__ vT,
    const void* __restrict__ maskp, u16* __restrict__ vals) {
  __shared__ u16 Kl[64 * 64];         // 8KB, XOR-8 swizzled rows
  __shared__ u16 Vl[64 * 64];         // 8KB
  __shared__ char Pl[8 * 16 * 144];   // per-wave [16 q][64 k] bf16, 144B rows

  // XCD-bijective swizzle (1024 blocks): each XCD gets 4 consecutive qt groups
  int bid = ((blockIdx.x & 7) << 7) | (blockIdx.x >> 3);
  int h = bid & 15, b = (bid >> 4) & 1, qt = bid >> 5;   // qt in [0,32)
  int tid = threadIdx.x;
  int lane = tid & 63, wid = tid >> 6;
  int fr = lane & 15, fg = lane >> 4;
  size_t bh = (size_t)b * Hc + h;
  int q0 = qt * 128;
  int q = q0 + wid * 16 + fr;        // this lane's q-row

  const u16* Qrow = qb + ((bh * Sc) + q) * (size_t)HDc;
  s16x8 qa0 = *(const s16x8*)(Qrow + fg * 8);
  s16x8 qa1 = *(const s16x8*)(Qrow + 32 + fg * 8);

  f32x4 o[4];                         // o[ef][r] = O[e=ef*16+fg*4+r][q]
#pragma unroll
  for (int ef = 0; ef < 4; ++ef) o[ef] = fzero4();
  float mrun = -1e30f, lrun = 0.f;

  const u16* Kg = kb + bh * (size_t)Sc * HDc;
  const u16* Vg = vT + bh * (size_t)HDc * Sc;
  char* pw = (char*)Pl + wid * 2304 + fr * 144;
  const float SCALE = 0.125f;
  const float LOG2E = 1.44269504088896340736f;

  // staging: wave w stages rows w*8..w*8+7 of each 64x64 tile (1KB per wave).
  // lane l: row = w*8 + (l>>3), src chunk sch = (l&7) ^ (row&7); LDS linear.
  int srow = wid * 8 + (lane >> 3);
  int sch = (lane & 7) ^ (srow & 7);
  const u16* KgS = Kg + (size_t)srow * HDc + sch * 8;
  const u16* VgS = Vg + (size_t)srow * Sc + sch * 8;
  char* KlD = (char*)Kl + wid * 1024;   // wave-uniform LDS dest
  char* VlD = (char*)Vl + wid * 1024;

  // fragment-read byte offsets (XOR-8 swizzled chunks)
  int kroff0 = fr * 128 + ((fg ^ (fr & 7)) << 4);
  int kroff1 = fr * 128 + (((4 + fg) ^ (fr & 7)) << 4);

  const u16* mk_b = (const u16*)maskp + ((size_t)b * Sc + q) * Sc + fg * 4;
  const float* mk_f = (const float*)maskp + ((size_t)b * Sc + q) * Sc + fg * 4;

  for (int kt = 0; kt < Sc / 64; ++kt) {
    // stage tile kt (K rows advance 64*HDc, V cols advance 64)
    gload_lds16(KgS + (size_t)kt * 4096, KlD);
    gload_lds16(VgS + (size_t)kt * 64, VlD);

    // mask loads (hide under the staging wait)
    ushort4 m4[4];
    float4 mf[4];
    if (MB) {
#pragma unroll
      for (int f = 0; f < 4; ++f) m4[f] = *(const ushort4*)(mk_b + kt * 64 + f * 16);
    } else {
#pragma unroll
      for (int f = 0; f < 4; ++f) mf[f] = *(const float4*)(mk_f + kt * 64 + f * 16);
    }
    __syncthreads();   // staging complete (drains vmcnt/lgkmcnt)

    // swapped QK^T: sa[f][r] = S[key = f*16+fg*4+r][q]
    f32x4 sa[4];
#pragma unroll
    for (int f = 0; f < 4; ++f) sa[f] = fzero4();
    __builtin_amdgcn_s_setprio(1);
#pragma unroll
    for (int f = 0; f < 4; ++f) {
      s16x8 kf = *(const s16x8*)((const char*)Kl + f * 2048 + kroff0);
      sa[f] = mfma16(kf, qa0, sa[f]);
    }
#pragma unroll
    for (int f = 0; f < 4; ++f) {
      s16x8 kf = *(const s16x8*)((const char*)Kl + f * 2048 + kroff1);
      sa[f] = mfma16(kf, qa1, sa[f]);
    }
    __builtin_amdgcn_s_setprio(0);

    // scale + mask
    float t[4][4];
#pragma unroll
    for (int f = 0; f < 4; ++f) {
      if (MB) {
        t[f][0] = fmaf(sa[f][0], SCALE, bf2f(m4[f].x));
        t[f][1] = fmaf(sa[f][1], SCALE, bf2f(m4[f].y));
        t[f][2] = fmaf(sa[f][2], SCALE, bf2f(m4[f].z));
        t[f][3] = fmaf(sa[f][3], SCALE, bf2f(m4[f].w));
      } else {
        t[f][0] = fmaf(sa[f][0], SCALE, mf[f].x);
        t[f][1] = fmaf(sa[f][1], SCALE, mf[f].y);
        t[f][2] = fmaf(sa[f][2], SCALE, mf[f].z);
        t[f][3] = fmaf(sa[f][3], SCALE, mf[f].w);
      }
    }

    // tile max (max3 tree) + cross-lane over fg groups
    float x0 = fmaxf(fmaxf(t[0][0], t[0][1]), t[0][2]);
    float x1 = fmaxf(fmaxf(t[0][3], t[1][0]), t[1][1]);
    float x2 = fmaxf(fmaxf(t[1][2], t[1][3]), t[2][0]);
    float x3 = fmaxf(fmaxf(t[2][1], t[2][2]), t[2][3]);
    float x4 = fmaxf(fmaxf(t[3][0], t[3][1]), t[3][2]);
    float mt = fmaxf(fmaxf(fmaxf(x0, x1), x2), fmaxf(fmaxf(x3, x4), t[3][3]));
    mt = fmaxf(mt, __shfl_xor(mt, 16, 64));
    mt = fmaxf(mt, __shfl_xor(mt, 32, 64));

    // defer-max: rescale only when the wave's max grew past threshold
    if (!__all(mt <= mrun + 8.0f)) {
      float mnew = fmaxf(mrun, mt);
      float al = __builtin_amdgcn_exp2f((mrun - mnew) * LOG2E);
      mrun = mnew;
      lrun *= al;
#pragma unroll
      for (int ef = 0; ef < 4; ++ef) o[ef] *= al;
    }

    float nm = -mrun * LOG2E;
    float p[4][4];
    float ss0 = 0.f, ss1 = 0.f;
#pragma unroll
    for (int f = 0; f < 4; ++f) {
      float p0 = __builtin_amdgcn_exp2f(fmaf(t[f][0], LOG2E, nm));
      float p1 = __builtin_amdgcn_exp2f(fmaf(t[f][1], LOG2E, nm));
      float p2 = __builtin_amdgcn_exp2f(fmaf(t[f][2], LOG2E, nm));
      float p3 = __builtin_amdgcn_exp2f(fmaf(t[f][3], LOG2E, nm));
      p[f][0] = p0; p[f][1] = p1; p[f][2] = p2; p[f][3] = p3;
      ss0 += (p0 + p1);
      ss1 += (p2 + p3);
    }
    float ssum = ss0 + ss1;
    ssum += __shfl_xor(ssum, 16, 64);
    ssum += __shfl_xor(ssum, 32, 64);
    lrun += ssum;

    // P -> per-wave LDS via packed cvt
#pragma unroll
    for (int f = 0; f < 4; ++f) {
      uint2 pk;
      pk.x = cvtpk_bf16(p[f][0], p[f][1]);
      pk.y = cvtpk_bf16(p[f][2], p[f][3]);
      *(uint2*)(pw + f * 32 + fg * 8) = pk;
    }

    // PV: O^T[e][q] += V^T[e][k] * P[q][k]
    s16x8 pa0 = *(const s16x8*)(pw + fg * 16);
    s16x8 pa1 = *(const s16x8*)(pw + 64 + fg * 16);
    __builtin_amdgcn_s_setprio(1);
#pragma unroll
    for (int ef = 0; ef < 4; ++ef) {
      s16x8 vf = *(const s16x8*)((const char*)Vl + ef * 2048 + kroff0);
      o[ef] = mfma16(vf, pa0, o[ef]);
    }
#pragma unroll
    for (int ef = 0; ef < 4; ++ef) {
      s16x8 vf = *(const s16x8*)((const char*)Vl + ef * 2048 + kroff1);
      o[ef] = mfma16(vf, pa1, o[ef]);
    }
    __builtin_amdgcn_s_setprio(0);

    __syncthreads();   // all waves done reading tile kt; next iter overwrites
  }

  // epilogue: normalize + store to vals in [B,H,S,HD]-flat order
  float inv = 1.f / lrun;
  u16* vbase = vals + (size_t)b * Sc * Dc + (size_t)h * Sc * HDc + (size_t)q * HDc;
#pragma unroll
  for (int ef = 0; ef < 4; ++ef) {
    ushort4 ov = make_ushort4(f2bf(o[ef][0] * inv), f2bf(o[ef][1] * inv),
                              f2bf(o[ef][2] * inv), f2bf(o[ef][3] * inv));
    *(ushort4*)(vbase + ef * 16 + fg * 4) = ov;
  }
}

extern "C" void kernel_launch(void* const* d_in, const int* in_sizes, int n_in,
                              void* d_out, int out_size, void* d_ws, size_t ws_size,
                              hipStream_t stream) {
  (void)in_sizes; (void)n_in; (void)out_size;
  const float* x    = (const float*)d_in[0];
  const float* mask = (const float*)d_in[1];
  const float* Wqkv = (const float*)d_in[2];
  const float* bqkv = (const float*)d_in[3];
  const float* Wo   = (const float*)d_in[4];
  const float* bo   = (const float*)d_in[5];
  float* out = (float*)d_out;
  char* ws = (char*)d_ws;

  u16* xb    = (u16*)(ws + 0);          // 16.8 MB   x as bf16 [8192][1024]
  u16* wqkvT = (u16*)(ws + 16777216);   // 6.3 MB    Wqkv^T bf16 [3072][1024]
  u16* woT   = (u16*)(ws + 23068672);   // 2.1 MB    Wo^T bf16 [1024][1024]
  u16* qb    = (u16*)(ws + 25165824);   // 16.8 MB   Q bf16 [B,H,S,64]
  u16* kb    = (u16*)(ws + 41943040);   // 16.8 MB   K bf16 [B,H,S,64]
  u16* vT    = (u16*)(ws + 58720256);   // 16.8 MB   V^T bf16 [B,H,64,S]
  u16* vals  = (u16*)(ws + 75497472);   // 16.8 MB   attn out bf16 (reshaped layout)
  u16* maskb = (u16*)(ws + 92274688);   // 67.1 MB   mask bf16 (natural domain)
  int use_mb = (ws_size >= 159383552ull) ? 1 : 0;

  cvt_f32_bf16<<<dim3(2048), dim3(256), 0, stream>>>(x, xb, (size_t)8388608);
  if (use_mb)
    cvt_f32_bf16<<<dim3(4096), dim3(256), 0, stream>>>(mask, maskb, (size_t)33554432);
  transpose_cvt<<<dim3(768), dim3(256), 0, stream>>>(Wqkv, wqkvT, 1024, 3072);
  transpose_cvt<<<dim3(256), dim3(256), 0, stream>>>(Wo, woT, 1024, 1024);

  gemm128<0><<<dim3(1536), dim3(256), 0, stream>>>(xb, wqkvT, bqkv, (void*)qb, kb, vT,
                                                   3072, 1024, 24);
  if (use_mb)
    attn_kernel<1><<<dim3(1024), dim3(512), 0, stream>>>(qb, kb, vT, (const void*)maskb, vals);
  else
    attn_kernel<0><<<dim3(1024), dim3(512), 0, stream>>>(qb, kb, vT, (const void*)mask, vals);
  gemm128<1><<<dim3(512), dim3(256), 0, stream>>>(vals, woT, bo, (void*)out, nullptr, nullptr,
                                                  1024, 1024, 8);
}

// Round 6
// 479.231 us; speedup vs baseline: 1.0380x; 1.0380x over previous
//
#include <hip/hip_runtime.h>
#include <hip/hip_bf16.h>

#define DEV __device__ __forceinline__

typedef unsigned short u16;
typedef __attribute__((ext_vector_type(4))) float f32x4;
typedef __attribute__((ext_vector_type(8))) short s16x8;

// problem constants
static constexpr int Bc = 2, Hc = 16, Sc = 4096, Dc = 1024, HDc = 64;

DEV u16 f2bf(float f) {
  unsigned x = __float_as_uint(f);
  x += 0x7FFFu + ((x >> 16) & 1u);   // RNE
  return (u16)(x >> 16);
}
DEV float bf2f(u16 u) { return __uint_as_float(((unsigned)u) << 16); }

DEV unsigned cvtpk_bf16(float lo, float hi) {   // word = bf16(lo) | bf16(hi)<<16
  unsigned r;
  asm("v_cvt_pk_bf16_f32 %0, %1, %2" : "=v"(r) : "v"(lo), "v"(hi));
  return r;
}

DEV void gload_lds16(const void* g, void* l) {
  __builtin_amdgcn_global_load_lds((const __attribute__((address_space(1))) void*)g,
                                   (__attribute__((address_space(3))) void*)l, 16, 0, 0);
}

DEV f32x4 mfma16(s16x8 a, s16x8 b, f32x4 c) {
  return __builtin_amdgcn_mfma_f32_16x16x32_bf16(a, b, c, 0, 0, 0);
}

DEV f32x4 fzero4() { f32x4 v; v[0] = v[1] = v[2] = v[3] = 0.f; return v; }

// ---------------- elementwise f32 -> bf16 ----------------
__global__ void cvt_f32_bf16(const float* __restrict__ in, u16* __restrict__ out, size_t n) {
  size_t i = ((size_t)blockIdx.x * blockDim.x + threadIdx.x) * 4;
  size_t stride = (size_t)gridDim.x * blockDim.x * 4;
  for (; i < n; i += stride) {
    float4 v = *(const float4*)(in + i);
    u16 a = f2bf(v.x), b = f2bf(v.y), c = f2bf(v.z), d = f2bf(v.w);
    *(ushort4*)(out + i) = make_ushort4(a, b, c, d);
  }
}

// ---------------- transpose + convert: out[c][r] = bf16(in[r][c]) ----------------
__global__ void transpose_cvt(const float* __restrict__ in, u16* __restrict__ out, int R, int C) {
  __shared__ u16 t[64][72];
  int nct = C >> 6;
  int tr = blockIdx.x / nct, tc = blockIdx.x % nct;
  int r0 = tr << 6, c0 = tc << 6;
  int lr = threadIdx.x >> 2;
  int lc0 = (threadIdx.x & 3) << 4;
  const float* src = in + (size_t)(r0 + lr) * C + c0 + lc0;
#pragma unroll
  for (int j = 0; j < 16; j += 4) {
    float4 v = *(const float4*)(src + j);
    t[lr][lc0 + j + 0] = f2bf(v.x);
    t[lr][lc0 + j + 1] = f2bf(v.y);
    t[lr][lc0 + j + 2] = f2bf(v.z);
    t[lr][lc0 + j + 3] = f2bf(v.w);
  }
  __syncthreads();
  u16* dst = out + (size_t)(c0 + lr) * R + r0 + lc0;
#pragma unroll
  for (int j = 0; j < 16; j += 4) {
    u16 a = t[lc0 + j + 0][lr], b = t[lc0 + j + 1][lr], c = t[lc0 + j + 2][lr], d = t[lc0 + j + 3][lr];
    *(ushort4*)(dst + j) = make_ushort4(a, b, c, d);
  }
}

// ---------------- GEMM: C[m][n] = A[m][:] . BT[n][:] + bias[n] ----------------
template <int MODE>
__global__ __launch_bounds__(256, 2) void gemm128(
    const u16* __restrict__ A, const u16* __restrict__ BT, const float* __restrict__ bias,
    void* __restrict__ out0, u16* __restrict__ out1, u16* __restrict__ out2,
    int N, int K, int grid_n) {
  __shared__ u16 Al[128 * 64];
  __shared__ u16 Bl[128 * 64];
  int bid = blockIdx.x;
  int bn = bid % grid_n, bm = bid / grid_n;
  int m0 = bm * 128, n0 = bn * 128;
  int tid = threadIdx.x, lane = tid & 63, wid = tid >> 6;
  int wm = wid >> 1, wn = wid & 1;
  int fr = lane & 15, fg = lane >> 4;

  f32x4 acc[4][4];
#pragma unroll
  for (int mi = 0; mi < 4; ++mi)
#pragma unroll
    for (int ni = 0; ni < 4; ++ni) acc[mi][ni] = fzero4();

  for (int kt = 0; kt < K; kt += 64) {
    const u16* Ag = A + (size_t)m0 * K + kt;
    const u16* Bg = BT + (size_t)n0 * K + kt;
#pragma unroll
    for (int it = 0; it < 4; ++it) {
      int L = it * 4096 + wid * 1024 + lane * 16;  // byte offset in 16KB tile
      int row = L >> 7;
      int sch = ((L >> 4) & 7) ^ (row & 7);
      gload_lds16(Ag + (size_t)row * K + sch * 8, (char*)Al + it * 4096 + wid * 1024);
      gload_lds16(Bg + (size_t)row * K + sch * 8, (char*)Bl + it * 4096 + wid * 1024);
    }
    __syncthreads();
#pragma unroll
    for (int c = 0; c < 2; ++c) {
      s16x8 af[4], bfr[4];
#pragma unroll
      for (int mi = 0; mi < 4; ++mi) {
        int row = wm * 64 + mi * 16 + fr;
        int ch = (c * 4 + fg) ^ (row & 7);
        af[mi] = *(const s16x8*)((const char*)Al + row * 128 + ch * 16);
      }
#pragma unroll
      for (int ni = 0; ni < 4; ++ni) {
        int row = wn * 64 + ni * 16 + fr;
        int ch = (c * 4 + fg) ^ (row & 7);
        bfr[ni] = *(const s16x8*)((const char*)Bl + row * 128 + ch * 16);
      }
#pragma unroll
      for (int mi = 0; mi < 4; ++mi)
#pragma unroll
        for (int ni = 0; ni < 4; ++ni) acc[mi][ni] = mfma16(af[mi], bfr[ni], acc[mi][ni]);
    }
    __syncthreads();
  }

  if constexpr (MODE == 0) {
    u16* qb = (u16*)out0;
    u16* kb = out1;
    u16* vT = out2;
#pragma unroll
    for (int ni = 0; ni < 4; ++ni) {
      int n = n0 + wn * 64 + ni * 16 + fr;
      float bv = bias[n];
      int h = n / 192;
      int c = n % 192;
      int part = c >> 6;
      int e = c & 63;
#pragma unroll
      for (int mi = 0; mi < 4; ++mi) {
        int m = m0 + wm * 64 + mi * 16 + fg * 4;
        int b = m >> 12;
        int s = m & 4095;
        size_t bh = (size_t)b * Hc + h;
        if (part == 2) {
          u16 a0 = f2bf(acc[mi][ni][0] + bv), a1 = f2bf(acc[mi][ni][1] + bv);
          u16 a2 = f2bf(acc[mi][ni][2] + bv), a3 = f2bf(acc[mi][ni][3] + bv);
          *(ushort4*)(vT + ((bh * HDc + e) * (size_t)Sc + s)) = make_ushort4(a0, a1, a2, a3);
        } else {
          u16* dst = (part == 0 ? qb : kb) + ((bh * Sc + s) * (size_t)HDc + e);
#pragma unroll
          for (int r = 0; r < 4; ++r) dst[(size_t)r * HDc] = f2bf(acc[mi][ni][r] + bv);
        }
      }
    }
  } else {
    float* O = (float*)out0;
#pragma unroll
    for (int ni = 0; ni < 4; ++ni) {
      int n = n0 + wn * 64 + ni * 16 + fr;
      float bv = bias[n];
#pragma unroll
      for (int mi = 0; mi < 4; ++mi) {
        int m = m0 + wm * 64 + mi * 16 + fg * 4;
#pragma unroll
        for (int r = 0; r < 4; ++r) O[(size_t)(m + r) * N + n] = acc[mi][ni][r] + bv;
      }
    }
  }
}

// ---------------- flash attention, split-phase staging ----------------
// grid 2048 = qt(64) x b(2) x h(16); block 256 = 4 waves; q-tile 64 rows.
// Single K-buffer + single V-buffer. Pipeline (2 barriers/tile, stages always
// in flight under a compute phase):
//   [V(t) in flight] mask(t+1)-ish loads + QK^T(t) from Kl
//   barrier  (drains V(t); Kl free)
//   issue K(t+1) -> Kl ; softmax(t) ; P->LDS ; PV(t) from Vl
//   barrier  (drains K(t+1); Vl free)
//   issue V(t+1) -> Vl
// MB=1: bf16 mask (natural domain); MB=0: f32 mask.
template <int MB>
__global__ __launch_bounds__(256, 6) void attn_kernel(
    const u16* __restrict__ qb, const u16* __restrict__ kb, const u16* __restrict__ vT,
    const void* __restrict__ maskp, u16* __restrict__ vals) {
  __shared__ u16 Kl[64 * 64];         // 8KB, XOR-8 swizzled rows
  __shared__ u16 Vl[64 * 64];         // 8KB
  __shared__ char Pl[4 * 16 * 144];   // per-wave [16 q][64 k] bf16, 144B rows

  // XCD-bijective swizzle: physical p*8+x -> logical x*256+p
  int bid = ((blockIdx.x & 7) << 8) | (blockIdx.x >> 3);
  int h = bid & 15, b = (bid >> 4) & 1, qt = bid >> 5;
  int tid = threadIdx.x;
  int lane = tid & 63, wid = tid >> 6;
  int fr = lane & 15, fg = lane >> 4;
  size_t bh = (size_t)b * Hc + h;
  int q0 = qt * 64;
  int q = q0 + wid * 16 + fr;        // this lane's q-row

  const u16* Qrow = qb + ((bh * Sc) + q) * (size_t)HDc;
  s16x8 qa0 = *(const s16x8*)(Qrow + fg * 8);
  s16x8 qa1 = *(const s16x8*)(Qrow + 32 + fg * 8);

  f32x4 o[4];                         // o[ef][r] = O[e=ef*16+fg*4+r][q]
#pragma unroll
  for (int ef = 0; ef < 4; ++ef) o[ef] = fzero4();
  float mrun = -1e30f, lrun = 0.f;

  const u16* Kg = kb + bh * (size_t)Sc * HDc;
  const u16* Vg = vT + bh * (size_t)HDc * Sc;
  char* pw = (char*)Pl + wid * 2304 + fr * 144;
  const float SCALE = 0.125f;
  const float LOG2E = 1.44269504088896340736f;

  // staging addresses: thread covers bytes L0 (rows 0..31) and L0+4096 (rows 32..63)
  int L0 = wid * 1024 + lane * 16;
  int L1 = L0 + 4096;
  int row0 = L0 >> 7, row1 = L1 >> 7;
  int sch0 = ((L0 >> 4) & 7) ^ (row0 & 7);
  int sch1 = ((L1 >> 4) & 7) ^ (row1 & 7);
  const u16* KgS0 = Kg + (size_t)row0 * HDc + sch0 * 8;   // + kt*4096 per tile
  const u16* KgS1 = Kg + (size_t)row1 * HDc + sch1 * 8;
  const u16* VgS0 = Vg + (size_t)row0 * Sc + sch0 * 8;    // + kt*64 per tile
  const u16* VgS1 = Vg + (size_t)row1 * Sc + sch1 * 8;
  char* KlD0 = (char*)Kl + L0;  char* KlD1 = (char*)Kl + L1;
  char* VlD0 = (char*)Vl + L0;  char* VlD1 = (char*)Vl + L1;

  // fragment-read byte offsets (XOR-8 swizzled chunks)
  int kroff0 = fr * 128 + ((fg ^ (fr & 7)) << 4);
  int kroff1 = fr * 128 + (((4 + fg) ^ (fr & 7)) << 4);

  const u16* mk_b = (const u16*)maskp + ((size_t)b * Sc + q) * Sc + fg * 4;
  const float* mk_f = (const float*)maskp + ((size_t)b * Sc + q) * Sc + fg * 4;

  constexpr int NT = Sc / 64;

  // prologue: stage K(0) and V(0)
  gload_lds16(KgS0, KlD0);
  gload_lds16(KgS1, KlD1);
  gload_lds16(VgS0, VlD0);
  gload_lds16(VgS1, VlD1);
  __syncthreads();

  for (int kt = 0; kt < NT; ++kt) {
    // mask loads for this tile (registers; consumed after QK^T)
    ushort4 m4[4];
    float4 mf[4];
    if (MB) {
#pragma unroll
      for (int f = 0; f < 4; ++f) m4[f] = *(const ushort4*)(mk_b + kt * 64 + f * 16);
    } else {
#pragma unroll
      for (int f = 0; f < 4; ++f) mf[f] = *(const float4*)(mk_f + kt * 64 + f * 16);
    }

    // swapped QK^T: sa[f][r] = S[key = f*16+fg*4+r][q]   (V(t) stage in flight)
    f32x4 sa[4];
#pragma unroll
    for (int f = 0; f < 4; ++f) sa[f] = fzero4();
    __builtin_amdgcn_s_setprio(1);
#pragma unroll
    for (int f = 0; f < 4; ++f) {
      s16x8 kf = *(const s16x8*)((const char*)Kl + f * 2048 + kroff0);
      sa[f] = mfma16(kf, qa0, sa[f]);
    }
#pragma unroll
    for (int f = 0; f < 4; ++f) {
      s16x8 kf = *(const s16x8*)((const char*)Kl + f * 2048 + kroff1);
      sa[f] = mfma16(kf, qa1, sa[f]);
    }
    __builtin_amdgcn_s_setprio(0);

    __syncthreads();   // V(t) visible; all waves done reading Kl

    // issue K(t+1) stage (flies under softmax + PV)
    if (kt + 1 < NT) {
      gload_lds16(KgS0 + (size_t)(kt + 1) * 4096, KlD0);
      gload_lds16(KgS1 + (size_t)(kt + 1) * 4096, KlD1);
    }

    // scale + mask
    float t[4][4];
#pragma unroll
    for (int f = 0; f < 4; ++f) {
      if (MB) {
        t[f][0] = fmaf(sa[f][0], SCALE, bf2f(m4[f].x));
        t[f][1] = fmaf(sa[f][1], SCALE, bf2f(m4[f].y));
        t[f][2] = fmaf(sa[f][2], SCALE, bf2f(m4[f].z));
        t[f][3] = fmaf(sa[f][3], SCALE, bf2f(m4[f].w));
      } else {
        t[f][0] = fmaf(sa[f][0], SCALE, mf[f].x);
        t[f][1] = fmaf(sa[f][1], SCALE, mf[f].y);
        t[f][2] = fmaf(sa[f][2], SCALE, mf[f].z);
        t[f][3] = fmaf(sa[f][3], SCALE, mf[f].w);
      }
    }

    // tile max (max3 tree) + cross-lane over fg groups
    float x0 = fmaxf(fmaxf(t[0][0], t[0][1]), t[0][2]);
    float x1 = fmaxf(fmaxf(t[0][3], t[1][0]), t[1][1]);
    float x2 = fmaxf(fmaxf(t[1][2], t[1][3]), t[2][0]);
    float x3 = fmaxf(fmaxf(t[2][1], t[2][2]), t[2][3]);
    float x4 = fmaxf(fmaxf(t[3][0], t[3][1]), t[3][2]);
    float mt = fmaxf(fmaxf(fmaxf(x0, x1), x2), fmaxf(fmaxf(x3, x4), t[3][3]));
    mt = fmaxf(mt, __shfl_xor(mt, 16, 64));
    mt = fmaxf(mt, __shfl_xor(mt, 32, 64));

    // defer-max: rescale only when the wave's max grew past threshold
    if (!__all(mt <= mrun + 8.0f)) {
      float mnew = fmaxf(mrun, mt);
      float al = __builtin_amdgcn_exp2f((mrun - mnew) * LOG2E);
      mrun = mnew;
      lrun *= al;
#pragma unroll
      for (int ef = 0; ef < 4; ++ef) o[ef] *= al;
    }

    float nm = -mrun * LOG2E;
    float p[4][4];
    float ss0 = 0.f, ss1 = 0.f;
#pragma unroll
    for (int f = 0; f < 4; ++f) {
      float p0 = __builtin_amdgcn_exp2f(fmaf(t[f][0], LOG2E, nm));
      float p1 = __builtin_amdgcn_exp2f(fmaf(t[f][1], LOG2E, nm));
      float p2 = __builtin_amdgcn_exp2f(fmaf(t[f][2], LOG2E, nm));
      float p3 = __builtin_amdgcn_exp2f(fmaf(t[f][3], LOG2E, nm));
      p[f][0] = p0; p[f][1] = p1; p[f][2] = p2; p[f][3] = p3;
      ss0 += (p0 + p1);
      ss1 += (p2 + p3);
    }
    float ssum = ss0 + ss1;
    ssum += __shfl_xor(ssum, 16, 64);
    ssum += __shfl_xor(ssum, 32, 64);
    lrun += ssum;

    // P -> per-wave LDS via packed cvt
#pragma unroll
    for (int f = 0; f < 4; ++f) {
      uint2 pk;
      pk.x = cvtpk_bf16(p[f][0], p[f][1]);
      pk.y = cvtpk_bf16(p[f][2], p[f][3]);
      *(uint2*)(pw + f * 32 + fg * 8) = pk;
    }

    // PV: O^T[e][q] += V^T[e][k] * P[q][k]
    s16x8 pa0 = *(const s16x8*)(pw + fg * 16);
    s16x8 pa1 = *(const s16x8*)(pw + 64 + fg * 16);
    __builtin_amdgcn_s_setprio(1);
#pragma unroll
    for (int ef = 0; ef < 4; ++ef) {
      s16x8 vf = *(const s16x8*)((const char*)Vl + ef * 2048 + kroff0);
      o[ef] = mfma16(vf, pa0, o[ef]);
    }
#pragma unroll
    for (int ef = 0; ef < 4; ++ef) {
      s16x8 vf = *(const s16x8*)((const char*)Vl + ef * 2048 + kroff1);
      o[ef] = mfma16(vf, pa1, o[ef]);
    }
    __builtin_amdgcn_s_setprio(0);

    __syncthreads();   // K(t+1) visible; all waves done reading Vl

    // issue V(t+1) stage (flies under next QK^T)
    if (kt + 1 < NT) {
      gload_lds16(VgS0 + (size_t)(kt + 1) * 64, VlD0);
      gload_lds16(VgS1 + (size_t)(kt + 1) * 64, VlD1);
    }
  }

  // epilogue: normalize + store to vals in [B,H,S,HD]-flat order
  float inv = 1.f / lrun;
  u16* vbase = vals + (size_t)b * Sc * Dc + (size_t)h * Sc * HDc + (size_t)q * HDc;
#pragma unroll
  for (int ef = 0; ef < 4; ++ef) {
    ushort4 ov = make_ushort4(f2bf(o[ef][0] * inv), f2bf(o[ef][1] * inv),
                              f2bf(o[ef][2] * inv), f2bf(o[ef][3] * inv));
    *(ushort4*)(vbase + ef * 16 + fg * 4) = ov;
  }
}

extern "C" void kernel_launch(void* const* d_in, const int* in_sizes, int n_in,
                              void* d_out, int out_size, void* d_ws, size_t ws_size,
                              hipStream_t stream) {
  (void)in_sizes; (void)n_in; (void)out_size;
  const float* x    = (const float*)d_in[0];
  const float* mask = (const float*)d_in[1];
  const float* Wqkv = (const float*)d_in[2];
  const float* bqkv = (const float*)d_in[3];
  const float* Wo   = (const float*)d_in[4];
  const float* bo   = (const float*)d_in[5];
  float* out = (float*)d_out;
  char* ws = (char*)d_ws;

  u16* xb    = (u16*)(ws + 0);          // 16.8 MB   x as bf16 [8192][1024]
  u16* wqkvT = (u16*)(ws + 16777216);   // 6.3 MB    Wqkv^T bf16 [3072][1024]
  u16* woT   = (u16*)(ws + 23068672);   // 2.1 MB    Wo^T bf16 [1024][1024]
  u16* qb    = (u16*)(ws + 25165824);   // 16.8 MB   Q bf16 [B,H,S,64]
  u16* kb    = (u16*)(ws + 41943040);   // 16.8 MB   K bf16 [B,H,S,64]
  u16* vT    = (u16*)(ws + 58720256);   // 16.8 MB   V^T bf16 [B,H,64,S]
  u16* vals  = (u16*)(ws + 75497472);   // 16.8 MB   attn out bf16 (reshaped layout)
  u16* maskb = (u16*)(ws + 92274688);   // 67.1 MB   mask bf16 (natural domain)
  int use_mb = (ws_size >= 159383552ull) ? 1 : 0;

  cvt_f32_bf16<<<dim3(2048), dim3(256), 0, stream>>>(x, xb, (size_t)8388608);
  if (use_mb)
    cvt_f32_bf16<<<dim3(4096), dim3(256), 0, stream>>>(mask, maskb, (size_t)33554432);
  transpose_cvt<<<dim3(768), dim3(256), 0, stream>>>(Wqkv, wqkvT, 1024, 3072);
  transpose_cvt<<<dim3(256), dim3(256), 0, stream>>>(Wo, woT, 1024, 1024);

  gemm128<0><<<dim3(1536), dim3(256), 0, stream>>>(xb, wqkvT, bqkv, (void*)qb, kb, vT,
                                                   3072, 1024, 24);
  if (use_mb)
    attn_kernel<1><<<dim3(2048), dim3(256), 0, stream>>>(qb, kb, vT, (const void*)maskb, vals);
  else
    attn_kernel<0><<<dim3(2048), dim3(256), 0, stream>>>(qb, kb, vT, (const void*)mask, vals);
  gemm128<1><<<dim3(512), dim3(256), 0, stream>>>(vals, woT, bo, (void*)out, nullptr, nullptr,
                                                  1024, 1024, 8);
}

// Round 7
// 447.057 us; speedup vs baseline: 1.1127x; 1.0720x over previous
//
#include <hip/hip_runtime.h>
#include <hip/hip_bf16.h>

#define DEV __device__ __forceinline__

typedef unsigned short u16;
typedef __attribute__((ext_vector_type(4))) float f32x4;
typedef __attribute__((ext_vector_type(8))) short s16x8;

// problem constants
static constexpr int Bc = 2, Hc = 16, Sc = 4096, Dc = 1024, HDc = 64;

DEV u16 f2bf(float f) {
  unsigned x = __float_as_uint(f);
  x += 0x7FFFu + ((x >> 16) & 1u);   // RNE
  return (u16)(x >> 16);
}
DEV float bf2f(u16 u) { return __uint_as_float(((unsigned)u) << 16); }

DEV unsigned cvtpk_bf16(float lo, float hi) {   // word = bf16(lo) | bf16(hi)<<16
  unsigned r;
  asm("v_cvt_pk_bf16_f32 %0, %1, %2" : "=v"(r) : "v"(lo), "v"(hi));
  return r;
}

DEV void gload_lds16(const void* g, void* l) {
  __builtin_amdgcn_global_load_lds((const __attribute__((address_space(1))) void*)g,
                                   (__attribute__((address_space(3))) void*)l, 16, 0, 0);
}

DEV f32x4 mfma16(s16x8 a, s16x8 b, f32x4 c) {
  return __builtin_amdgcn_mfma_f32_16x16x32_bf16(a, b, c, 0, 0, 0);
}

DEV f32x4 fzero4() { f32x4 v; v[0] = v[1] = v[2] = v[3] = 0.f; return v; }

// ---------------- elementwise f32 -> bf16 ----------------
__global__ void cvt_f32_bf16(const float* __restrict__ in, u16* __restrict__ out, size_t n) {
  size_t i = ((size_t)blockIdx.x * blockDim.x + threadIdx.x) * 4;
  size_t stride = (size_t)gridDim.x * blockDim.x * 4;
  for (; i < n; i += stride) {
    float4 v = *(const float4*)(in + i);
    u16 a = f2bf(v.x), b = f2bf(v.y), c = f2bf(v.z), d = f2bf(v.w);
    *(ushort4*)(out + i) = make_ushort4(a, b, c, d);
  }
}

// ---------------- transpose + convert: out[c][r] = bf16(in[r][c]) ----------------
__global__ void transpose_cvt(const float* __restrict__ in, u16* __restrict__ out, int R, int C) {
  __shared__ u16 t[64][72];
  int nct = C >> 6;
  int tr = blockIdx.x / nct, tc = blockIdx.x % nct;
  int r0 = tr << 6, c0 = tc << 6;
  int lr = threadIdx.x >> 2;
  int lc0 = (threadIdx.x & 3) << 4;
  const float* src = in + (size_t)(r0 + lr) * C + c0 + lc0;
#pragma unroll
  for (int j = 0; j < 16; j += 4) {
    float4 v = *(const float4*)(src + j);
    t[lr][lc0 + j + 0] = f2bf(v.x);
    t[lr][lc0 + j + 1] = f2bf(v.y);
    t[lr][lc0 + j + 2] = f2bf(v.z);
    t[lr][lc0 + j + 3] = f2bf(v.w);
  }
  __syncthreads();
  u16* dst = out + (size_t)(c0 + lr) * R + r0 + lc0;
#pragma unroll
  for (int j = 0; j < 16; j += 4) {
    u16 a = t[lc0 + j + 0][lr], b = t[lc0 + j + 1][lr], c = t[lc0 + j + 2][lr], d = t[lc0 + j + 3][lr];
    *(ushort4*)(dst + j) = make_ushort4(a, b, c, d);
  }
}

// ---------------- GEMM: C[m][n] = A[m][:] . BT[n][:] + bias[n] ----------------
template <int MODE>
__global__ __launch_bounds__(256, 2) void gemm128(
    const u16* __restrict__ A, const u16* __restrict__ BT, const float* __restrict__ bias,
    void* __restrict__ out0, u16* __restrict__ out1, u16* __restrict__ out2,
    int N, int K, int grid_n) {
  __shared__ u16 Al[128 * 64];
  __shared__ u16 Bl[128 * 64];
  int bid = blockIdx.x;
  int bn = bid % grid_n, bm = bid / grid_n;
  int m0 = bm * 128, n0 = bn * 128;
  int tid = threadIdx.x, lane = tid & 63, wid = tid >> 6;
  int wm = wid >> 1, wn = wid & 1;
  int fr = lane & 15, fg = lane >> 4;

  f32x4 acc[4][4];
#pragma unroll
  for (int mi = 0; mi < 4; ++mi)
#pragma unroll
    for (int ni = 0; ni < 4; ++ni) acc[mi][ni] = fzero4();

  for (int kt = 0; kt < K; kt += 64) {
    const u16* Ag = A + (size_t)m0 * K + kt;
    const u16* Bg = BT + (size_t)n0 * K + kt;
#pragma unroll
    for (int it = 0; it < 4; ++it) {
      int L = it * 4096 + wid * 1024 + lane * 16;  // byte offset in 16KB tile
      int row = L >> 7;
      int sch = ((L >> 4) & 7) ^ (row & 7);
      gload_lds16(Ag + (size_t)row * K + sch * 8, (char*)Al + it * 4096 + wid * 1024);
      gload_lds16(Bg + (size_t)row * K + sch * 8, (char*)Bl + it * 4096 + wid * 1024);
    }
    __syncthreads();
#pragma unroll
    for (int c = 0; c < 2; ++c) {
      s16x8 af[4], bfr[4];
#pragma unroll
      for (int mi = 0; mi < 4; ++mi) {
        int row = wm * 64 + mi * 16 + fr;
        int ch = (c * 4 + fg) ^ (row & 7);
        af[mi] = *(const s16x8*)((const char*)Al + row * 128 + ch * 16);
      }
#pragma unroll
      for (int ni = 0; ni < 4; ++ni) {
        int row = wn * 64 + ni * 16 + fr;
        int ch = (c * 4 + fg) ^ (row & 7);
        bfr[ni] = *(const s16x8*)((const char*)Bl + row * 128 + ch * 16);
      }
#pragma unroll
      for (int mi = 0; mi < 4; ++mi)
#pragma unroll
        for (int ni = 0; ni < 4; ++ni) acc[mi][ni] = mfma16(af[mi], bfr[ni], acc[mi][ni]);
    }
    __syncthreads();
  }

  if constexpr (MODE == 0) {
    u16* qb = (u16*)out0;
    u16* kb = out1;
    u16* vT = out2;
#pragma unroll
    for (int ni = 0; ni < 4; ++ni) {
      int n = n0 + wn * 64 + ni * 16 + fr;
      float bv = bias[n];
      int h = n / 192;
      int c = n % 192;
      int part = c >> 6;
      int e = c & 63;
#pragma unroll
      for (int mi = 0; mi < 4; ++mi) {
        int m = m0 + wm * 64 + mi * 16 + fg * 4;
        int b = m >> 12;
        int s = m & 4095;
        size_t bh = (size_t)b * Hc + h;
        if (part == 2) {
          u16 a0 = f2bf(acc[mi][ni][0] + bv), a1 = f2bf(acc[mi][ni][1] + bv);
          u16 a2 = f2bf(acc[mi][ni][2] + bv), a3 = f2bf(acc[mi][ni][3] + bv);
          *(ushort4*)(vT + ((bh * HDc + e) * (size_t)Sc + s)) = make_ushort4(a0, a1, a2, a3);
        } else {
          u16* dst = (part == 0 ? qb : kb) + ((bh * Sc + s) * (size_t)HDc + e);
#pragma unroll
          for (int r = 0; r < 4; ++r) dst[(size_t)r * HDc] = f2bf(acc[mi][ni][r] + bv);
        }
      }
    }
  } else {
    float* O = (float*)out0;
#pragma unroll
    for (int ni = 0; ni < 4; ++ni) {
      int n = n0 + wn * 64 + ni * 16 + fr;
      float bv = bias[n];
#pragma unroll
      for (int mi = 0; mi < 4; ++mi) {
        int m = m0 + wm * 64 + mi * 16 + fg * 4;
#pragma unroll
        for (int r = 0; r < 4; ++r) O[(size_t)(m + r) * N + n] = acc[mi][ni][r] + bv;
      }
    }
  }
}

// ---------------- flash attention, split-phase staging, identity dispatch ----------------
// grid 2048 = qt(64) x b(2) x h(16), h FASTEST in dispatch order: the 16 blocks
// sharing a mask row-slice launch simultaneously across XCDs -> L3/L2 temporal
// reuse (this was the R2-measured low-fetch configuration; the XCD swizzle
// serialized sharers onto one XCD and tripled FETCH_SIZE).
// block 256 = 4 waves; q-tile 64 rows. Single K-buffer + single V-buffer:
//   [V(t) in flight] mask(t) loads + QK^T(t) from Kl
//   barrier (drains V(t))  -> issue K(t+1) ; softmax ; P->LDS ; PV(t) from Vl
//   barrier (drains K(t+1)) -> issue V(t+1)
template <int MB>
__global__ __launch_bounds__(256, 6) void attn_kernel(
    const u16* __restrict__ qb, const u16* __restrict__ kb, const u16* __restrict__ vT,
    const void* __restrict__ maskp, u16* __restrict__ vals) {
  __shared__ u16 Kl[64 * 64];         // 8KB, XOR-8 swizzled rows
  __shared__ u16 Vl[64 * 64];         // 8KB
  __shared__ char Pl[4 * 16 * 144];   // per-wave [16 q][64 k] bf16, 144B rows

  int bid = blockIdx.x;               // identity order (locality via dispatch time)
  int h = bid & 15, b = (bid >> 4) & 1, qt = bid >> 5;
  int tid = threadIdx.x;
  int lane = tid & 63, wid = tid >> 6;
  int fr = lane & 15, fg = lane >> 4;
  size_t bh = (size_t)b * Hc + h;
  int q0 = qt * 64;
  int q = q0 + wid * 16 + fr;        // this lane's q-row

  const u16* Qrow = qb + ((bh * Sc) + q) * (size_t)HDc;
  s16x8 qa0 = *(const s16x8*)(Qrow + fg * 8);
  s16x8 qa1 = *(const s16x8*)(Qrow + 32 + fg * 8);

  f32x4 o[4];                         // o[ef][r] = O[e=ef*16+fg*4+r][q]
#pragma unroll
  for (int ef = 0; ef < 4; ++ef) o[ef] = fzero4();
  float mrun = -1e30f, lrun = 0.f;

  const u16* Kg = kb + bh * (size_t)Sc * HDc;
  const u16* Vg = vT + bh * (size_t)HDc * Sc;
  char* pw = (char*)Pl + wid * 2304 + fr * 144;
  const float SCALE = 0.125f;
  const float LOG2E = 1.44269504088896340736f;

  // staging addresses: thread covers bytes L0 (rows 0..31) and L0+4096 (rows 32..63)
  int L0 = wid * 1024 + lane * 16;
  int L1 = L0 + 4096;
  int row0 = L0 >> 7, row1 = L1 >> 7;
  int sch0 = ((L0 >> 4) & 7) ^ (row0 & 7);
  int sch1 = ((L1 >> 4) & 7) ^ (row1 & 7);
  const u16* KgS0 = Kg + (size_t)row0 * HDc + sch0 * 8;   // + kt*4096 per tile
  const u16* KgS1 = Kg + (size_t)row1 * HDc + sch1 * 8;
  const u16* VgS0 = Vg + (size_t)row0 * Sc + sch0 * 8;    // + kt*64 per tile
  const u16* VgS1 = Vg + (size_t)row1 * Sc + sch1 * 8;
  char* KlD0 = (char*)Kl + L0;  char* KlD1 = (char*)Kl + L1;
  char* VlD0 = (char*)Vl + L0;  char* VlD1 = (char*)Vl + L1;

  // fragment-read byte offsets (XOR-8 swizzled chunks)
  int kroff0 = fr * 128 + ((fg ^ (fr & 7)) << 4);
  int kroff1 = fr * 128 + (((4 + fg) ^ (fr & 7)) << 4);

  const u16* mk_b = (const u16*)maskp + ((size_t)b * Sc + q) * Sc + fg * 4;
  const float* mk_f = (const float*)maskp + ((size_t)b * Sc + q) * Sc + fg * 4;

  constexpr int NT = Sc / 64;

  // prologue: stage K(0) and V(0)
  gload_lds16(KgS0, KlD0);
  gload_lds16(KgS1, KlD1);
  gload_lds16(VgS0, VlD0);
  gload_lds16(VgS1, VlD1);
  __syncthreads();

  for (int kt = 0; kt < NT; ++kt) {
    // mask loads for this tile (registers; consumed after QK^T)
    ushort4 m4[4];
    float4 mf[4];
    if (MB) {
#pragma unroll
      for (int f = 0; f < 4; ++f) m4[f] = *(const ushort4*)(mk_b + kt * 64 + f * 16);
    } else {
#pragma unroll
      for (int f = 0; f < 4; ++f) mf[f] = *(const float4*)(mk_f + kt * 64 + f * 16);
    }

    // swapped QK^T: sa[f][r] = S[key = f*16+fg*4+r][q]   (V(t) stage in flight)
    f32x4 sa[4];
#pragma unroll
    for (int f = 0; f < 4; ++f) sa[f] = fzero4();
    __builtin_amdgcn_s_setprio(1);
#pragma unroll
    for (int f = 0; f < 4; ++f) {
      s16x8 kf = *(const s16x8*)((const char*)Kl + f * 2048 + kroff0);
      sa[f] = mfma16(kf, qa0, sa[f]);
    }
#pragma unroll
    for (int f = 0; f < 4; ++f) {
      s16x8 kf = *(const s16x8*)((const char*)Kl + f * 2048 + kroff1);
      sa[f] = mfma16(kf, qa1, sa[f]);
    }
    __builtin_amdgcn_s_setprio(0);

    __syncthreads();   // V(t) visible; all waves done reading Kl

    // issue K(t+1) stage (flies under softmax + PV)
    if (kt + 1 < NT) {
      gload_lds16(KgS0 + (size_t)(kt + 1) * 4096, KlD0);
      gload_lds16(KgS1 + (size_t)(kt + 1) * 4096, KlD1);
    }

    // scale + mask
    float t[4][4];
#pragma unroll
    for (int f = 0; f < 4; ++f) {
      if (MB) {
        t[f][0] = fmaf(sa[f][0], SCALE, bf2f(m4[f].x));
        t[f][1] = fmaf(sa[f][1], SCALE, bf2f(m4[f].y));
        t[f][2] = fmaf(sa[f][2], SCALE, bf2f(m4[f].z));
        t[f][3] = fmaf(sa[f][3], SCALE, bf2f(m4[f].w));
      } else {
        t[f][0] = fmaf(sa[f][0], SCALE, mf[f].x);
        t[f][1] = fmaf(sa[f][1], SCALE, mf[f].y);
        t[f][2] = fmaf(sa[f][2], SCALE, mf[f].z);
        t[f][3] = fmaf(sa[f][3], SCALE, mf[f].w);
      }
    }

    // tile max (max3 tree) + cross-lane over fg groups
    float x0 = fmaxf(fmaxf(t[0][0], t[0][1]), t[0][2]);
    float x1 = fmaxf(fmaxf(t[0][3], t[1][0]), t[1][1]);
    float x2 = fmaxf(fmaxf(t[1][2], t[1][3]), t[2][0]);
    float x3 = fmaxf(fmaxf(t[2][1], t[2][2]), t[2][3]);
    float x4 = fmaxf(fmaxf(t[3][0], t[3][1]), t[3][2]);
    float mt = fmaxf(fmaxf(fmaxf(x0, x1), x2), fmaxf(fmaxf(x3, x4), t[3][3]));
    mt = fmaxf(mt, __shfl_xor(mt, 16, 64));
    mt = fmaxf(mt, __shfl_xor(mt, 32, 64));

    // defer-max: rescale only when the wave's max grew past threshold
    if (!__all(mt <= mrun + 8.0f)) {
      float mnew = fmaxf(mrun, mt);
      float al = __builtin_amdgcn_exp2f((mrun - mnew) * LOG2E);
      mrun = mnew;
      lrun *= al;
#pragma unroll
      for (int ef = 0; ef < 4; ++ef) o[ef] *= al;
    }

    float nm = -mrun * LOG2E;
    float p[4][4];
    float ss0 = 0.f, ss1 = 0.f;
#pragma unroll
    for (int f = 0; f < 4; ++f) {
      float p0 = __builtin_amdgcn_exp2f(fmaf(t[f][0], LOG2E, nm));
      float p1 = __builtin_amdgcn_exp2f(fmaf(t[f][1], LOG2E, nm));
      float p2 = __builtin_amdgcn_exp2f(fmaf(t[f][2], LOG2E, nm));
      float p3 = __builtin_amdgcn_exp2f(fmaf(t[f][3], LOG2E, nm));
      p[f][0] = p0; p[f][1] = p1; p[f][2] = p2; p[f][3] = p3;
      ss0 += (p0 + p1);
      ss1 += (p2 + p3);
    }
    float ssum = ss0 + ss1;
    ssum += __shfl_xor(ssum, 16, 64);
    ssum += __shfl_xor(ssum, 32, 64);
    lrun += ssum;

    // P -> per-wave LDS via packed cvt
#pragma unroll
    for (int f = 0; f < 4; ++f) {
      uint2 pk;
      pk.x = cvtpk_bf16(p[f][0], p[f][1]);
      pk.y = cvtpk_bf16(p[f][2], p[f][3]);
      *(uint2*)(pw + f * 32 + fg * 8) = pk;
    }

    // PV: O^T[e][q] += V^T[e][k] * P[q][k]
    s16x8 pa0 = *(const s16x8*)(pw + fg * 16);
    s16x8 pa1 = *(const s16x8*)(pw + 64 + fg * 16);
    __builtin_amdgcn_s_setprio(1);
#pragma unroll
    for (int ef = 0; ef < 4; ++ef) {
      s16x8 vf = *(const s16x8*)((const char*)Vl + ef * 2048 + kroff0);
      o[ef] = mfma16(vf, pa0, o[ef]);
    }
#pragma unroll
    for (int ef = 0; ef < 4; ++ef) {
      s16x8 vf = *(const s16x8*)((const char*)Vl + ef * 2048 + kroff1);
      o[ef] = mfma16(vf, pa1, o[ef]);
    }
    __builtin_amdgcn_s_setprio(0);

    __syncthreads();   // K(t+1) visible; all waves done reading Vl

    // issue V(t+1) stage (flies under next QK^T)
    if (kt + 1 < NT) {
      gload_lds16(VgS0 + (size_t)(kt + 1) * 64, VlD0);
      gload_lds16(VgS1 + (size_t)(kt + 1) * 64, VlD1);
    }
  }

  // epilogue: normalize + store to vals in [B,H,S,HD]-flat order
  float inv = 1.f / lrun;
  u16* vbase = vals + (size_t)b * Sc * Dc + (size_t)h * Sc * HDc + (size_t)q * HDc;
#pragma unroll
  for (int ef = 0; ef < 4; ++ef) {
    ushort4 ov = make_ushort4(f2bf(o[ef][0] * inv), f2bf(o[ef][1] * inv),
                              f2bf(o[ef][2] * inv), f2bf(o[ef][3] * inv));
    *(ushort4*)(vbase + ef * 16 + fg * 4) = ov;
  }
}

extern "C" void kernel_launch(void* const* d_in, const int* in_sizes, int n_in,
                              void* d_out, int out_size, void* d_ws, size_t ws_size,
                              hipStream_t stream) {
  (void)in_sizes; (void)n_in; (void)out_size;
  const float* x    = (const float*)d_in[0];
  const float* mask = (const float*)d_in[1];
  const float* Wqkv = (const float*)d_in[2];
  const float* bqkv = (const float*)d_in[3];
  const float* Wo   = (const float*)d_in[4];
  const float* bo   = (const float*)d_in[5];
  float* out = (float*)d_out;
  char* ws = (char*)d_ws;

  u16* xb    = (u16*)(ws + 0);          // 16.8 MB   x as bf16 [8192][1024]
  u16* wqkvT = (u16*)(ws + 16777216);   // 6.3 MB    Wqkv^T bf16 [3072][1024]
  u16* woT   = (u16*)(ws + 23068672);   // 2.1 MB    Wo^T bf16 [1024][1024]
  u16* qb    = (u16*)(ws + 25165824);   // 16.8 MB   Q bf16 [B,H,S,64]
  u16* kb    = (u16*)(ws + 41943040);   // 16.8 MB   K bf16 [B,H,S,64]
  u16* vT    = (u16*)(ws + 58720256);   // 16.8 MB   V^T bf16 [B,H,64,S]
  u16* vals  = (u16*)(ws + 75497472);   // 16.8 MB   attn out bf16 (reshaped layout)
  u16* maskb = (u16*)(ws + 92274688);   // 67.1 MB   mask bf16 (natural domain)
  int use_mb = (ws_size >= 159383552ull) ? 1 : 0;

  cvt_f32_bf16<<<dim3(2048), dim3(256), 0, stream>>>(x, xb, (size_t)8388608);
  if (use_mb)
    cvt_f32_bf16<<<dim3(4096), dim3(256), 0, stream>>>(mask, maskb, (size_t)33554432);
  transpose_cvt<<<dim3(768), dim3(256), 0, stream>>>(Wqkv, wqkvT, 1024, 3072);
  transpose_cvt<<<dim3(256), dim3(256), 0, stream>>>(Wo, woT, 1024, 1024);

  gemm128<0><<<dim3(1536), dim3(256), 0, stream>>>(xb, wqkvT, bqkv, (void*)qb, kb, vT,
                                                   3072, 1024, 24);
  if (use_mb)
    attn_kernel<1><<<dim3(2048), dim3(256), 0, stream>>>(qb, kb, vT, (const void*)maskb, vals);
  else
    attn_kernel<0><<<dim3(2048), dim3(256), 0, stream>>>(qb, kb, vT, (const void*)mask, vals);
  gemm128<1><<<dim3(512), dim3(256), 0, stream>>>(vals, woT, bo, (void*)out, nullptr, nullptr,
                                                  1024, 1024, 8);
}

// Round 8
// 440.358 us; speedup vs baseline: 1.1297x; 1.0152x over previous
//
#include <hip/hip_runtime.h>
#include <hip/hip_bf16.h>

#define DEV __device__ __forceinline__

typedef unsigned short u16;
typedef __attribute__((ext_vector_type(4))) float f32x4;
typedef __attribute__((ext_vector_type(8))) short s16x8;

// problem constants
static constexpr int Bc = 2, Hc = 16, Sc = 4096, Dc = 1024, HDc = 64;

DEV u16 f2bf(float f) {
  unsigned x = __float_as_uint(f);
  x += 0x7FFFu + ((x >> 16) & 1u);   // RNE
  return (u16)(x >> 16);
}
DEV float bf2f(u16 u) { return __uint_as_float(((unsigned)u) << 16); }

DEV unsigned cvtpk_bf16(float lo, float hi) {   // word = bf16(lo) | bf16(hi)<<16
  unsigned r;
  asm("v_cvt_pk_bf16_f32 %0, %1, %2" : "=v"(r) : "v"(lo), "v"(hi));
  return r;
}

DEV void gload_lds16(const void* g, void* l) {
  __builtin_amdgcn_global_load_lds((const __attribute__((address_space(1))) void*)g,
                                   (__attribute__((address_space(3))) void*)l, 16, 0, 0);
}

DEV f32x4 mfma16(s16x8 a, s16x8 b, f32x4 c) {
  return __builtin_amdgcn_mfma_f32_16x16x32_bf16(a, b, c, 0, 0, 0);
}

DEV f32x4 fzero4() { f32x4 v; v[0] = v[1] = v[2] = v[3] = 0.f; return v; }

// log2-domain constants
#define LOG2E_F 1.44269504088896340736f
#define QSCALE_F (0.125f * LOG2E_F)        // folds 1/sqrt(64) and ln->log2
#define MBIAS_F (12.0f * LOG2E_F)          // fixed softmax "max" (exact invariance)

// ---------------- elementwise f32 -> bf16 with affine transform ----------------
__global__ void cvt_f32_bf16(const float* __restrict__ in, u16* __restrict__ out, size_t n,
                             float scale, float bias) {
  size_t i = ((size_t)blockIdx.x * blockDim.x + threadIdx.x) * 4;
  size_t stride = (size_t)gridDim.x * blockDim.x * 4;
  for (; i < n; i += stride) {
    float4 v = *(const float4*)(in + i);
    u16 a = f2bf(fmaf(v.x, scale, bias)), b = f2bf(fmaf(v.y, scale, bias));
    u16 c = f2bf(fmaf(v.z, scale, bias)), d = f2bf(fmaf(v.w, scale, bias));
    *(ushort4*)(out + i) = make_ushort4(a, b, c, d);
  }
}

// ---------------- transpose + convert: out[c][r] = bf16(in[r][c]) ----------------
__global__ void transpose_cvt(const float* __restrict__ in, u16* __restrict__ out, int R, int C) {
  __shared__ u16 t[64][72];
  int nct = C >> 6;
  int tr = blockIdx.x / nct, tc = blockIdx.x % nct;
  int r0 = tr << 6, c0 = tc << 6;
  int lr = threadIdx.x >> 2;
  int lc0 = (threadIdx.x & 3) << 4;
  const float* src = in + (size_t)(r0 + lr) * C + c0 + lc0;
#pragma unroll
  for (int j = 0; j < 16; j += 4) {
    float4 v = *(const float4*)(src + j);
    t[lr][lc0 + j + 0] = f2bf(v.x);
    t[lr][lc0 + j + 1] = f2bf(v.y);
    t[lr][lc0 + j + 2] = f2bf(v.z);
    t[lr][lc0 + j + 3] = f2bf(v.w);
  }
  __syncthreads();
  u16* dst = out + (size_t)(c0 + lr) * R + r0 + lc0;
#pragma unroll
  for (int j = 0; j < 16; j += 4) {
    u16 a = t[lc0 + j + 0][lr], b = t[lc0 + j + 1][lr], c = t[lc0 + j + 2][lr], d = t[lc0 + j + 3][lr];
    *(ushort4*)(dst + j) = make_ushort4(a, b, c, d);
  }
}

// ---------------- GEMM: C[m][n] = A[m][:] . BT[n][:] + bias[n] ----------------
// MODE 0: QKV scatter epilogue; Q additionally scaled by QSCALE_F (log2-domain attn).
template <int MODE>
__global__ __launch_bounds__(256, 2) void gemm128(
    const u16* __restrict__ A, const u16* __restrict__ BT, const float* __restrict__ bias,
    void* __restrict__ out0, u16* __restrict__ out1, u16* __restrict__ out2,
    int N, int K, int grid_n) {
  __shared__ u16 Al[128 * 64];
  __shared__ u16 Bl[128 * 64];
  int bid = blockIdx.x;
  int bn = bid % grid_n, bm = bid / grid_n;
  int m0 = bm * 128, n0 = bn * 128;
  int tid = threadIdx.x, lane = tid & 63, wid = tid >> 6;
  int wm = wid >> 1, wn = wid & 1;
  int fr = lane & 15, fg = lane >> 4;

  f32x4 acc[4][4];
#pragma unroll
  for (int mi = 0; mi < 4; ++mi)
#pragma unroll
    for (int ni = 0; ni < 4; ++ni) acc[mi][ni] = fzero4();

  for (int kt = 0; kt < K; kt += 64) {
    const u16* Ag = A + (size_t)m0 * K + kt;
    const u16* Bg = BT + (size_t)n0 * K + kt;
#pragma unroll
    for (int it = 0; it < 4; ++it) {
      int L = it * 4096 + wid * 1024 + lane * 16;  // byte offset in 16KB tile
      int row = L >> 7;
      int sch = ((L >> 4) & 7) ^ (row & 7);
      gload_lds16(Ag + (size_t)row * K + sch * 8, (char*)Al + it * 4096 + wid * 1024);
      gload_lds16(Bg + (size_t)row * K + sch * 8, (char*)Bl + it * 4096 + wid * 1024);
    }
    __syncthreads();
#pragma unroll
    for (int c = 0; c < 2; ++c) {
      s16x8 af[4], bfr[4];
#pragma unroll
      for (int mi = 0; mi < 4; ++mi) {
        int row = wm * 64 + mi * 16 + fr;
        int ch = (c * 4 + fg) ^ (row & 7);
        af[mi] = *(const s16x8*)((const char*)Al + row * 128 + ch * 16);
      }
#pragma unroll
      for (int ni = 0; ni < 4; ++ni) {
        int row = wn * 64 + ni * 16 + fr;
        int ch = (c * 4 + fg) ^ (row & 7);
        bfr[ni] = *(const s16x8*)((const char*)Bl + row * 128 + ch * 16);
      }
#pragma unroll
      for (int mi = 0; mi < 4; ++mi)
#pragma unroll
        for (int ni = 0; ni < 4; ++ni) acc[mi][ni] = mfma16(af[mi], bfr[ni], acc[mi][ni]);
    }
    __syncthreads();
  }

  if constexpr (MODE == 0) {
    u16* qb = (u16*)out0;
    u16* kb = out1;
    u16* vT = out2;
#pragma unroll
    for (int ni = 0; ni < 4; ++ni) {
      int n = n0 + wn * 64 + ni * 16 + fr;
      float bv = bias[n];
      int h = n / 192;
      int c = n % 192;
      int part = c >> 6;
      int e = c & 63;
#pragma unroll
      for (int mi = 0; mi < 4; ++mi) {
        int m = m0 + wm * 64 + mi * 16 + fg * 4;
        int b = m >> 12;
        int s = m & 4095;
        size_t bh = (size_t)b * Hc + h;
        if (part == 2) {
          u16 a0 = f2bf(acc[mi][ni][0] + bv), a1 = f2bf(acc[mi][ni][1] + bv);
          u16 a2 = f2bf(acc[mi][ni][2] + bv), a3 = f2bf(acc[mi][ni][3] + bv);
          *(ushort4*)(vT + ((bh * HDc + e) * (size_t)Sc + s)) = make_ushort4(a0, a1, a2, a3);
        } else if (part == 0) {
          u16* dst = qb + ((bh * Sc + s) * (size_t)HDc + e);
#pragma unroll
          for (int r = 0; r < 4; ++r)
            dst[(size_t)r * HDc] = f2bf((acc[mi][ni][r] + bv) * QSCALE_F);
        } else {
          u16* dst = kb + ((bh * Sc + s) * (size_t)HDc + e);
#pragma unroll
          for (int r = 0; r < 4; ++r) dst[(size_t)r * HDc] = f2bf(acc[mi][ni][r] + bv);
        }
      }
    }
  } else {
    float* O = (float*)out0;
#pragma unroll
    for (int ni = 0; ni < 4; ++ni) {
      int n = n0 + wn * 64 + ni * 16 + fr;
      float bv = bias[n];
#pragma unroll
      for (int mi = 0; mi < 4; ++mi) {
        int m = m0 + wm * 64 + mi * 16 + fg * 4;
#pragma unroll
        for (int r = 0; r < 4; ++r) O[(size_t)(m + r) * N + n] = acc[mi][ni][r] + bv;
      }
    }
  }
}

// ---------------- flash attention, fixed-max softmax (no online rescale) ----------------
// Softmax is invariant to the subtracted constant: use m=12 folded into the
// precomputed operands (Q pre-scaled by 0.125*log2e, mask pre-mapped to
// mask*log2e - 12*log2e). QK^T MFMA accumulates ON TOP of the mask values
// (acc init = mask), so p = exp2(acc) with zero intervening VALU. lrun is a
// pure per-lane partial sum; cross-lane reduction happens once after the loop.
// grid 2048 = qt(64) x b(2) x h(16), h fastest (identity dispatch = L3 reuse).
// Split-phase staging: V(t) flies under QK^T(t); K(t+1) flies under softmax+PV(t).
template <int MB>
__global__ __launch_bounds__(256, 6) void attn_kernel(
    const u16* __restrict__ qb, const u16* __restrict__ kb, const u16* __restrict__ vT,
    const void* __restrict__ maskp, u16* __restrict__ vals) {
  __shared__ u16 Kl[64 * 64];         // 8KB, XOR-8 swizzled rows
  __shared__ u16 Vl[64 * 64];         // 8KB
  __shared__ char Pl[4 * 16 * 144];   // per-wave [16 q][64 k] bf16, 144B rows

  int bid = blockIdx.x;               // identity order (locality via dispatch time)
  int h = bid & 15, b = (bid >> 4) & 1, qt = bid >> 5;
  int tid = threadIdx.x;
  int lane = tid & 63, wid = tid >> 6;
  int fr = lane & 15, fg = lane >> 4;
  size_t bh = (size_t)b * Hc + h;
  int q0 = qt * 64;
  int q = q0 + wid * 16 + fr;        // this lane's q-row

  const u16* Qrow = qb + ((bh * Sc) + q) * (size_t)HDc;
  s16x8 qa0 = *(const s16x8*)(Qrow + fg * 8);
  s16x8 qa1 = *(const s16x8*)(Qrow + 32 + fg * 8);

  f32x4 o[4];                         // o[ef][r] = O[e=ef*16+fg*4+r][q]
#pragma unroll
  for (int ef = 0; ef < 4; ++ef) o[ef] = fzero4();
  float lrun = 0.f;                   // per-lane partial of sum_k exp2(S'[k][q])

  const u16* Kg = kb + bh * (size_t)Sc * HDc;
  const u16* Vg = vT + bh * (size_t)HDc * Sc;
  char* pw = (char*)Pl + wid * 2304 + fr * 144;

  // staging addresses: thread covers bytes L0 (rows 0..31) and L0+4096 (rows 32..63)
  int L0 = wid * 1024 + lane * 16;
  int L1 = L0 + 4096;
  int row0 = L0 >> 7, row1 = L1 >> 7;
  int sch0 = ((L0 >> 4) & 7) ^ (row0 & 7);
  int sch1 = ((L1 >> 4) & 7) ^ (row1 & 7);
  const u16* KgS0 = Kg + (size_t)row0 * HDc + sch0 * 8;   // + kt*4096 per tile
  const u16* KgS1 = Kg + (size_t)row1 * HDc + sch1 * 8;
  const u16* VgS0 = Vg + (size_t)row0 * Sc + sch0 * 8;    // + kt*64 per tile
  const u16* VgS1 = Vg + (size_t)row1 * Sc + sch1 * 8;
  char* KlD0 = (char*)Kl + L0;  char* KlD1 = (char*)Kl + L1;
  char* VlD0 = (char*)Vl + L0;  char* VlD1 = (char*)Vl + L1;

  // fragment-read byte offsets (XOR-8 swizzled chunks)
  int kroff0 = fr * 128 + ((fg ^ (fr & 7)) << 4);
  int kroff1 = fr * 128 + (((4 + fg) ^ (fr & 7)) << 4);

  const u16* mk_b = (const u16*)maskp + ((size_t)b * Sc + q) * Sc + fg * 4;
  const float* mk_f = (const float*)maskp + ((size_t)b * Sc + q) * Sc + fg * 4;

  constexpr int NT = Sc / 64;

  // prologue: stage K(0) and V(0)
  gload_lds16(KgS0, KlD0);
  gload_lds16(KgS1, KlD1);
  gload_lds16(VgS0, VlD0);
  gload_lds16(VgS1, VlD1);
  __syncthreads();

  for (int kt = 0; kt < NT; ++kt) {
    // mask loads for this tile -> QK^T accumulator init (log2-domain, pre-biased)
    f32x4 sa[4];
    if (MB) {
#pragma unroll
      for (int f = 0; f < 4; ++f) {
        ushort4 m4 = *(const ushort4*)(mk_b + kt * 64 + f * 16);
        sa[f][0] = bf2f(m4.x); sa[f][1] = bf2f(m4.y);
        sa[f][2] = bf2f(m4.z); sa[f][3] = bf2f(m4.w);
      }
    } else {
#pragma unroll
      for (int f = 0; f < 4; ++f) {
        float4 mf = *(const float4*)(mk_f + kt * 64 + f * 16);
        sa[f][0] = fmaf(mf.x, LOG2E_F, -MBIAS_F);
        sa[f][1] = fmaf(mf.y, LOG2E_F, -MBIAS_F);
        sa[f][2] = fmaf(mf.z, LOG2E_F, -MBIAS_F);
        sa[f][3] = fmaf(mf.w, LOG2E_F, -MBIAS_F);
      }
    }

    // swapped QK^T on top of mask: sa[f][r] = Q'.K + mask'  (V(t) stage in flight)
    __builtin_amdgcn_s_setprio(1);
#pragma unroll
    for (int f = 0; f < 4; ++f) {
      s16x8 kf = *(const s16x8*)((const char*)Kl + f * 2048 + kroff0);
      sa[f] = mfma16(kf, qa0, sa[f]);
    }
#pragma unroll
    for (int f = 0; f < 4; ++f) {
      s16x8 kf = *(const s16x8*)((const char*)Kl + f * 2048 + kroff1);
      sa[f] = mfma16(kf, qa1, sa[f]);
    }
    __builtin_amdgcn_s_setprio(0);

    __syncthreads();   // V(t) visible; all waves done reading Kl

    // issue K(t+1) stage (flies under softmax + PV)
    if (kt + 1 < NT) {
      gload_lds16(KgS0 + (size_t)(kt + 1) * 4096, KlD0);
      gload_lds16(KgS1 + (size_t)(kt + 1) * 4096, KlD1);
    }

    // p = exp2(S') directly; accumulate per-lane denominator partials
    float p[4][4];
#pragma unroll
    for (int f = 0; f < 4; ++f) {
      float p0 = __builtin_amdgcn_exp2f(sa[f][0]);
      float p1 = __builtin_amdgcn_exp2f(sa[f][1]);
      float p2 = __builtin_amdgcn_exp2f(sa[f][2]);
      float p3 = __builtin_amdgcn_exp2f(sa[f][3]);
      p[f][0] = p0; p[f][1] = p1; p[f][2] = p2; p[f][3] = p3;
      lrun += (p0 + p1) + (p2 + p3);
    }

    // P -> per-wave LDS via packed cvt
#pragma unroll
    for (int f = 0; f < 4; ++f) {
      uint2 pk;
      pk.x = cvtpk_bf16(p[f][0], p[f][1]);
      pk.y = cvtpk_bf16(p[f][2], p[f][3]);
      *(uint2*)(pw + f * 32 + fg * 8) = pk;
    }

    // PV: O^T[e][q] += V^T[e][k] * P[q][k]
    s16x8 pa0 = *(const s16x8*)(pw + fg * 16);
    s16x8 pa1 = *(const s16x8*)(pw + 64 + fg * 16);
    __builtin_amdgcn_s_setprio(1);
#pragma unroll
    for (int ef = 0; ef < 4; ++ef) {
      s16x8 vf = *(const s16x8*)((const char*)Vl + ef * 2048 + kroff0);
      o[ef] = mfma16(vf, pa0, o[ef]);
    }
#pragma unroll
    for (int ef = 0; ef < 4; ++ef) {
      s16x8 vf = *(const s16x8*)((const char*)Vl + ef * 2048 + kroff1);
      o[ef] = mfma16(vf, pa1, o[ef]);
    }
    __builtin_amdgcn_s_setprio(0);

    __syncthreads();   // K(t+1) visible; all waves done reading Vl

    // issue V(t+1) stage (flies under next QK^T)
    if (kt + 1 < NT) {
      gload_lds16(VgS0 + (size_t)(kt + 1) * 64, VlD0);
      gload_lds16(VgS1 + (size_t)(kt + 1) * 64, VlD1);
    }
  }

  // cross-lane denominator reduction (once, not per tile)
  lrun += __shfl_xor(lrun, 16, 64);
  lrun += __shfl_xor(lrun, 32, 64);
  float inv = 1.f / lrun;

  // epilogue: normalize + store to vals in [B,H,S,HD]-flat order
  u16* vbase = vals + (size_t)b * Sc * Dc + (size_t)h * Sc * HDc + (size_t)q * HDc;
#pragma unroll
  for (int ef = 0; ef < 4; ++ef) {
    ushort4 ov = make_ushort4(f2bf(o[ef][0] * inv), f2bf(o[ef][1] * inv),
                              f2bf(o[ef][2] * inv), f2bf(o[ef][3] * inv));
    *(ushort4*)(vbase + ef * 16 + fg * 4) = ov;
  }
}

extern "C" void kernel_launch(void* const* d_in, const int* in_sizes, int n_in,
                              void* d_out, int out_size, void* d_ws, size_t ws_size,
                              hipStream_t stream) {
  (void)in_sizes; (void)n_in; (void)out_size;
  const float* x    = (const float*)d_in[0];
  const float* mask = (const float*)d_in[1];
  const float* Wqkv = (const float*)d_in[2];
  const float* bqkv = (const float*)d_in[3];
  const float* Wo   = (const float*)d_in[4];
  const float* bo   = (const float*)d_in[5];
  float* out = (float*)d_out;
  char* ws = (char*)d_ws;

  u16* xb    = (u16*)(ws + 0);          // 16.8 MB   x as bf16 [8192][1024]
  u16* wqkvT = (u16*)(ws + 16777216);   // 6.3 MB    Wqkv^T bf16 [3072][1024]
  u16* woT   = (u16*)(ws + 23068672);   // 2.1 MB    Wo^T bf16 [1024][1024]
  u16* qb    = (u16*)(ws + 25165824);   // 16.8 MB   Q' bf16 (pre-scaled) [B,H,S,64]
  u16* kb    = (u16*)(ws + 41943040);   // 16.8 MB   K bf16 [B,H,S,64]
  u16* vT    = (u16*)(ws + 58720256);   // 16.8 MB   V^T bf16 [B,H,64,S]
  u16* vals  = (u16*)(ws + 75497472);   // 16.8 MB   attn out bf16 (reshaped layout)
  u16* maskb = (u16*)(ws + 92274688);   // 67.1 MB   mask' = bf16(mask*log2e - 12*log2e)
  int use_mb = (ws_size >= 159383552ull) ? 1 : 0;

  cvt_f32_bf16<<<dim3(2048), dim3(256), 0, stream>>>(x, xb, (size_t)8388608, 1.0f, 0.0f);
  if (use_mb)
    cvt_f32_bf16<<<dim3(4096), dim3(256), 0, stream>>>(mask, maskb, (size_t)33554432,
                                                       LOG2E_F, -MBIAS_F);
  transpose_cvt<<<dim3(768), dim3(256), 0, stream>>>(Wqkv, wqkvT, 1024, 3072);
  transpose_cvt<<<dim3(256), dim3(256), 0, stream>>>(Wo, woT, 1024, 1024);

  gemm128<0><<<dim3(1536), dim3(256), 0, stream>>>(xb, wqkvT, bqkv, (void*)qb, kb, vT,
                                                   3072, 1024, 24);
  if (use_mb)
    attn_kernel<1><<<dim3(2048), dim3(256), 0, stream>>>(qb, kb, vT, (const void*)maskb, vals);
  else
    attn_kernel<0><<<dim3(2048), dim3(256), 0, stream>>>(qb, kb, vT, (const void*)mask, vals);
  gemm128<1><<<dim3(512), dim3(256), 0, stream>>>(vals, woT, bo, (void*)out, nullptr, nullptr,
                                                  1024, 1024, 8);
}